// Round 10
// baseline (863.355 us; speedup 1.0000x reference)
//
#include <hip/hip_runtime.h>
#include <hip/hip_cooperative_groups.h>
#include <math.h>

namespace cg = cooperative_groups;

// Problem dims
#define BL    6
#define CCH   64
#define C3    192
#define L2    1024
#define DIC   128
#define NST   16
#define K4    4
#define PSTR  1088   // padded plane stride: 34 rows * 32 cols
#define NCH   32     // scan chunks per sequence (32 steps each)

#define LOG2E 1.44269504088896340736f
#define LN2C  0.69314718055994530942f

__device__ __forceinline__ float fexp(float x){ return __builtin_amdgcn_exp2f(x*LOG2E); }
__device__ __forceinline__ float fsilu(float x){ return x / (1.f + fexp(-x)); }
__device__ __forceinline__ float fsoftplus(float x){
  if (x > 20.f) return x;
  return __builtin_amdgcn_logf(1.f + fexp(x)) * LN2C;
}
__device__ __forceinline__ float fgelu(float x){
  return 0.5f*x*(1.f + erff(x*0.70710678118654752440f));
}

struct MegaP {
  const float *img,*dz,*sg,*norm_g,*norm_b,*gn1_g,*gn1_b,*conv1_w,*conv1_b,
              *gn2_g,*gn2_b,*conv2_w,*conv2_b,*skip_w,*skip_b,*ln1_g,*ln1_b,
              *ln2_g,*ln2_b,*in_proj_w,*dwconv_w,*dwconv_b,*x_proj_w,
              *dt_proj_w,*dt_proj_b,*A_logs,*Ds,*out_norm_g,*out_norm_b,
              *out_proj_w,*fc1_w,*fc1_b,*fc2_w,*fc2_b;
  float *x3c,*xact1,*h1,*xact2,*xp,*x_cmaj,*z_t,*xc,*xconv,*dtp,*ys_t,*xv;
  float *psum1,*psq1,*psum2,*psq2;
  float *part1,*part2,*hend,*prodA,*u_t,*Bp,*Cp;
  float *out;
};

// conv row helper
__device__ __forceinline__ void conv_row_acc(float4& a0, float4& a1, float4 mid, float lf, float rt,
    const float* wp0, const float* wp1){
  float w0=wp0[0], w1=wp0[1], w2=wp0[2];
  a0.x = fmaf(w0,lf,   fmaf(w1,mid.x, fmaf(w2,mid.y, a0.x)));
  a0.y = fmaf(w0,mid.x,fmaf(w1,mid.y, fmaf(w2,mid.z, a0.y)));
  a0.z = fmaf(w0,mid.y,fmaf(w1,mid.z, fmaf(w2,mid.w, a0.z)));
  a0.w = fmaf(w0,mid.z,fmaf(w1,mid.w, fmaf(w2,rt,    a0.w)));
  float v0=wp1[0], v1=wp1[1], v2=wp1[2];
  a1.x = fmaf(v0,lf,   fmaf(v1,mid.x, fmaf(v2,mid.y, a1.x)));
  a1.y = fmaf(v0,mid.x,fmaf(v1,mid.y, fmaf(v2,mid.z, a1.y)));
  a1.z = fmaf(v0,mid.y,fmaf(v1,mid.z, fmaf(v2,mid.w, a1.z)));
  a1.w = fmaf(v0,mid.z,fmaf(v1,mid.w, fmaf(v2,rt,    a1.w)));
}

__device__ __forceinline__ void conv_ci_body(float4 m0, float4 m1, float4 m2, int q,
    const float* wp0, const float* wp1, float4& a0, float4& a1){
  float lf0=__shfl_up(m0.w,1,64), rt0=__shfl_down(m0.x,1,64);
  float lf1=__shfl_up(m1.w,1,64), rt1=__shfl_down(m1.x,1,64);
  float lf2=__shfl_up(m2.w,1,64), rt2=__shfl_down(m2.x,1,64);
  if (q==0){ lf0=0.f; lf1=0.f; lf2=0.f; }
  if (q==7){ rt0=0.f; rt1=0.f; rt2=0.f; }
  conv_row_acc(a0,a1,m0,lf0,rt0, wp0+0, wp1+0);
  conv_row_acc(a0,a1,m1,lf1,rt1, wp0+3, wp1+3);
  conv_row_acc(a0,a1,m2,lf2,rt2, wp0+6, wp1+6);
}

// scan pixel for direction k, chunk ch (32 steps), step j
__device__ __forceinline__ int scan_pix32(int ch, int j, int k){
  if (k==0) return ch*32 + j;
  if (k==1) return j*32 + ch;
  if (k==2) return 1023 - (ch*32 + j);
  return 1023 - (j*32 + ch);
}

struct StepB { float dtv, uv; float4 B0,B1,B2,B3; };
__device__ __forceinline__ StepB loadB(const float* db, const float* ub, const float* Bb, int p){
  StepB r;
  r.dtv = db[(size_t)p*DIC]; r.uv = ub[(size_t)p*DIC];
  const float* bp = Bb + p*NST;
  r.B0 = *(const float4*)bp; r.B1 = *(const float4*)(bp+4);
  r.B2 = *(const float4*)(bp+8); r.B3 = *(const float4*)(bp+12);
  return r;
}

// ===== phase bodies (vb = virtual block index, tid = threadIdx.x) =====

__device__ __forceinline__ void p0_ln2d(int vb, int tid, const MegaP& P, float* smem){
  float* ps = smem;        // [4][64]
  float* pq = smem + 256;  // [4][64]
  int s = vb >> 4;
  int lane = tid & 63;
  int cgp = tid >> 6;
  int p = ((vb & 15) << 6) + lane;
  int bsmp = s/3;
  const float* fr = P.img + (size_t)s*CCH*L2;
  float vals[16]; float sm=0.f, sq=0.f;
  #pragma unroll
  for (int j=0;j<16;++j){
    int c = cgp*16+j;
    float v = fr[c*L2+p];
    vals[j]=v; sm+=v; sq+=v*v;
  }
  ps[cgp*64+lane]=sm; pq[cgp*64+lane]=sq;
  __syncthreads();
  sm = ps[lane]+ps[64+lane]+ps[128+lane]+ps[192+lane];
  sq = pq[lane]+pq[64+lane]+pq[128+lane]+pq[192+lane];
  float mean = sm*(1.f/CCH); float var = sq*(1.f/CCH) - mean*mean;
  float rs = rsqrtf(var + 1e-6f);
  float* o = P.x3c + (size_t)s*C3*L2;
  const float* dzp = P.dz + (size_t)bsmp*CCH*L2;
  const float* sgp = P.sg + (size_t)bsmp*CCH*L2;
  float gsm=0.f, gsq=0.f;
  #pragma unroll
  for (int j=0;j<16;++j){
    int c = cgp*16+j;
    float dzv = dzp[c*L2+p];
    float nv  = (vals[j]-mean)*rs*P.norm_g[c] + P.norm_b[c];
    float sgv = sgp[c*L2+p];
    o[c*L2+p] = dzv;
    o[(CCH+c)*L2+p] = nv;
    o[(2*CCH+c)*L2+p] = sgv;
    gsm += dzv+nv+sgv; gsq += dzv*dzv+nv*nv+sgv*sgv;
  }
  for (int m=1;m<64;m<<=1){ gsm+=__shfl_xor(gsm,m,64); gsq+=__shfl_xor(gsq,m,64); }
  __syncthreads();
  if (lane==0){ ps[cgp*64]=gsm; pq[cgp*64]=gsq; }
  __syncthreads();
  if (tid==0){
    atomicAdd(P.psum1+s, ps[0]+ps[64]+ps[128]+ps[192]);
    atomicAdd(P.psq1 +s, pq[0]+pq[64]+pq[128]+pq[192]);
  }
}

__device__ __forceinline__ void gnact_body(int vb, int tid, const float* __restrict__ x,
    const float* __restrict__ psum, const float* __restrict__ psq,
    const float* __restrict__ g, const float* __restrict__ b,
    int ch, float inv_n, float eps, float* __restrict__ out){
  int s = vb / ch; int c = vb % ch;
  float mean = psum[s]*inv_n;
  float var = psq[s]*inv_n - mean*mean;
  float rs = rsqrtf(var + eps);
  float gc = g[c]*rs; float bc = b[c] - mean*rs*g[c];
  float4 v = *(const float4*)(x + (size_t)vb*1024 + tid*4);
  float4 o; o.x = fsilu(v.x*gc+bc); o.y = fsilu(v.y*gc+bc);
  o.z = fsilu(v.z*gc+bc); o.w = fsilu(v.w*gc+bc);
  float* pl = out + (size_t)vb*PSTR;
  *(float4*)(pl + 32 + tid*4) = o;
  float4 z4 = make_float4(0.f,0.f,0.f,0.f);
  if (tid < 8)  *(float4*)(pl + tid*4) = z4;
  else if (tid < 16) *(float4*)(pl + 1056 + (tid-8)*4) = z4;
}

__device__ __forceinline__ void p2_conv1(int vb, int tid, const MegaP& P){
  int kk = vb&7; int cop=(vb>>3)&31; int s=vb>>8;
  int co0 = cop*2, co1 = co0+1;
  int row = tid>>3; int q = tid&7; int col0 = q*4;
  float4 a0 = make_float4(0.f,0.f,0.f,0.f);
  float4 a1 = make_float4(0.f,0.f,0.f,0.f);
  int ci0 = kk*24;
  const float* pl = P.xact1 + ((size_t)s*C3 + ci0)*PSTR + row*32 + col0;
  const float* wp0 = P.conv1_w + (size_t)(co0*C3 + ci0)*9;
  const float* wp1 = P.conv1_w + (size_t)(co1*C3 + ci0)*9;
  float4 m0 = *(const float4*)(pl);
  float4 m1 = *(const float4*)(pl+32);
  float4 m2 = *(const float4*)(pl+64);
  #pragma unroll 2
  for (int i=0;i<24;++i){
    const float* pn = pl + (i<23 ? PSTR : 0);
    float4 n0 = *(const float4*)(pn);
    float4 n1 = *(const float4*)(pn+32);
    float4 n2 = *(const float4*)(pn+64);
    conv_ci_body(m0,m1,m2,q, wp0, wp1, a0, a1);
    wp0 += 9; wp1 += 9; pl = pn; m0=n0; m1=n1; m2=n2;
  }
  float* pp = P.part1 + (size_t)kk*(BL*CCH*L2) + ((size_t)s*CCH+co0)*L2 + row*32+col0;
  *(float4*)pp = a0;
  *(float4*)(pp+L2) = a1;
}

__device__ __forceinline__ void p3_reduce1(int vb, int tid, const MegaP& P, float* smem){
  float* s_sm = smem; float* s_sq = smem+4;
  int co = vb & 63; int s = vb >> 6;
  size_t ofs = ((size_t)s*CCH+co)*L2 + tid*4;
  const size_t stride = (size_t)BL*CCH*L2;
  float4 acc = *(const float4*)(P.part1 + ofs);
  #pragma unroll
  for (int kk=1;kk<8;++kk){
    float4 r = *(const float4*)(P.part1 + (size_t)kk*stride + ofs);
    acc.x += r.x; acc.y += r.y; acc.z += r.z; acc.w += r.w;
  }
  float bv = P.conv1_b[co];
  acc.x += bv; acc.y += bv; acc.z += bv; acc.w += bv;
  *(float4*)(P.h1 + ofs) = acc;
  float sm = acc.x+acc.y+acc.z+acc.w;
  float sq = acc.x*acc.x+acc.y*acc.y+acc.z*acc.z+acc.w*acc.w;
  for (int m=1;m<64;m<<=1){ sm+=__shfl_xor(sm,m,64); sq+=__shfl_xor(sq,m,64); }
  int wv = tid>>6;
  if ((tid&63)==0){ s_sm[wv]=sm; s_sq[wv]=sq; }
  __syncthreads();
  if (tid==0){
    atomicAdd(P.psum2+s, s_sm[0]+s_sm[1]+s_sm[2]+s_sm[3]);
    atomicAdd(P.psq2 +s, s_sq[0]+s_sq[1]+s_sq[2]+s_sq[3]);
  }
}

__device__ __forceinline__ void p5_conv2(int vb, int tid, const MegaP& P){
  int t2 = vb; int role = t2 % 3; t2 /= 3;
  int cop = t2 & 31; int s = t2 >> 5;
  int co0 = cop*2, co1 = co0+1;
  int row = tid>>3; int q = tid&7; int col0 = q*4;
  int p = row*32+col0;
  float4 a0 = make_float4(0.f,0.f,0.f,0.f);
  float4 a1 = make_float4(0.f,0.f,0.f,0.f);
  if (role < 2){
    int ci0 = role*32;
    const float* pl = P.xact2 + ((size_t)s*CCH + ci0)*PSTR + row*32 + col0;
    const float* wp0 = P.conv2_w + (size_t)(co0*CCH + ci0)*9;
    const float* wp1 = P.conv2_w + (size_t)(co1*CCH + ci0)*9;
    float4 m0 = *(const float4*)(pl);
    float4 m1 = *(const float4*)(pl+32);
    float4 m2 = *(const float4*)(pl+64);
    #pragma unroll 2
    for (int i=0;i<32;++i){
      const float* pn = pl + (i<31 ? PSTR : 0);
      float4 n0 = *(const float4*)(pn);
      float4 n1 = *(const float4*)(pn+32);
      float4 n2 = *(const float4*)(pn+64);
      conv_ci_body(m0,m1,m2,q, wp0, wp1, a0, a1);
      wp0 += 9; wp1 += 9; pl = pn; m0=n0; m1=n1; m2=n2;
    }
  } else {
    const float* x3 = P.x3c + (size_t)s*C3*L2 + p;
    #pragma unroll 4
    for (int ci=0; ci<C3; ++ci){
      float4 v = *(const float4*)(x3 + (size_t)ci*L2);
      float ws0 = P.skip_w[co0*C3+ci], ws1 = P.skip_w[co1*C3+ci];
      a0.x = fmaf(ws0,v.x,a0.x); a0.y = fmaf(ws0,v.y,a0.y); a0.z = fmaf(ws0,v.z,a0.z); a0.w = fmaf(ws0,v.w,a0.w);
      a1.x = fmaf(ws1,v.x,a1.x); a1.y = fmaf(ws1,v.y,a1.y); a1.z = fmaf(ws1,v.z,a1.z); a1.w = fmaf(ws1,v.w,a1.w);
    }
  }
  float* pp = P.part2 + (size_t)role*(BL*CCH*L2) + ((size_t)s*CCH+co0)*L2 + p;
  *(float4*)pp = a0;
  *(float4*)(pp+L2) = a1;
}

__device__ __forceinline__ void p6_reduce2(int vb, int tid, const MegaP& P){
  int co = vb & 63; int s = vb >> 6;
  int p = tid*4;
  size_t ofs = ((size_t)s*CCH+co)*L2 + p;
  const size_t stride = (size_t)BL*CCH*L2;
  float4 r0 = *(const float4*)(P.part2 + ofs);
  float4 r1 = *(const float4*)(P.part2 + stride + ofs);
  float4 r2 = *(const float4*)(P.part2 + 2*stride + ofs);
  float bv = P.conv2_b[co]+P.skip_b[co];
  float4 o;
  o.x = r0.x+r1.x+r2.x+bv;
  o.y = r0.y+r1.y+r2.y+bv;
  o.z = r0.z+r1.z+r2.z+bv;
  o.w = r0.w+r1.w+r2.w+bv;
  *(float4*)(P.x_cmaj + ofs) = o;
  float* xpb = P.xp + ((size_t)s*L2 + p)*CCH + co;
  xpb[0] = o.x; xpb[CCH] = o.y; xpb[2*CCH] = o.z; xpb[3*CCH] = o.w;
}

__device__ __forceinline__ void p7_ln1_inproj(int vb, int tid, const MegaP& P, float* xn_s){
  int oq = vb & 3; int pg = (vb>>2)&15; int s = vb>>6;
  int p0 = pg*64;
  int wv = __builtin_amdgcn_readfirstlane(tid>>6); int lane = tid&63;
  for (int j=0;j<16;++j){
    int pl = wv*16 + j; int p = p0 + pl;
    float v = P.xp[((size_t)s*L2 + p)*CCH + lane];
    float sm = v, sq = v*v;
    for (int m=1;m<64;m<<=1){ sm += __shfl_xor(sm,m,64); sq += __shfl_xor(sq,m,64); }
    float mean = sm*(1.f/64.f); float var = sq*(1.f/64.f) - mean*mean;
    float rs = rsqrtf(var + 1e-5f);
    xn_s[pl*65 + lane] = (v-mean)*rs*P.ln1_g[lane] + P.ln1_b[lane];
  }
  __syncthreads();
  int px_l = tid & 63;
  int og = __builtin_amdgcn_readfirstlane(tid >> 6);
  int o0 = oq*64 + og*16;
  float acc[16];
  #pragma unroll
  for (int oi=0;oi<16;++oi) acc[oi]=0.f;
  for (int c=0;c<64;++c){
    float xv = xn_s[px_l*65 + c];
    #pragma unroll
    for (int oi=0;oi<16;++oi) acc[oi] = fmaf(P.in_proj_w[(o0+oi)*64 + c], xv, acc[oi]);
  }
  int p = p0 + px_l;
  if (oq < 2){
    #pragma unroll
    for (int oi=0;oi<16;++oi) P.xc[((size_t)s*DIC + o0 + oi)*L2 + p] = acc[oi];
  } else {
    #pragma unroll
    for (int oi=0;oi<16;++oi) P.z_t[((size_t)s*DIC + (o0-128) + oi)*L2 + p] = acc[oi];
  }
}

__device__ __forceinline__ void p8_dwconv(int vb, int tid, const MegaP& P){
  int dch = vb & 127; int s = vb >> 7;
  int row = tid>>3; int q = tid&7; int col0 = q*4;
  const float* xr = P.xc + ((size_t)s*DIC+dch)*L2;
  const float* wp = P.dwconv_w + dch*9;
  float bv = P.dwconv_b[dch];
  float4 acc = make_float4(bv,bv,bv,bv);
  #pragma unroll
  for (int dy=-1;dy<=1;++dy){
    int r = row+dy;
    float4 mid = make_float4(0.f,0.f,0.f,0.f);
    if (0<=r && r<32) mid = *(const float4*)(xr + r*32 + col0);
    float lf = __shfl_up(mid.w,1,64); if(q==0) lf=0.f;
    float rt = __shfl_down(mid.x,1,64); if(q==7) rt=0.f;
    float w0=wp[(dy+1)*3], w1=wp[(dy+1)*3+1], w2=wp[(dy+1)*3+2];
    acc.x = fmaf(w0,lf,   fmaf(w1,mid.x, fmaf(w2,mid.y, acc.x)));
    acc.y = fmaf(w0,mid.x,fmaf(w1,mid.y, fmaf(w2,mid.z, acc.y)));
    acc.z = fmaf(w0,mid.y,fmaf(w1,mid.z, fmaf(w2,mid.w, acc.z)));
    acc.w = fmaf(w0,mid.z,fmaf(w1,mid.w, fmaf(w2,rt,    acc.w)));
  }
  acc.x = fsilu(acc.x); acc.y = fsilu(acc.y); acc.z = fsilu(acc.z); acc.w = fsilu(acc.w);
  *(float4*)(P.xconv + ((size_t)s*DIC+dch)*L2 + row*32+col0) = acc;
}

__device__ __forceinline__ void p9_xproj_dt(int vb, int tid, const MegaP& P, float* smem){
  int pg = vb & 15; int sk = vb >> 4;
  int k = sk & 3; int s = sk >> 2;
  for (int i = tid; i < 128*16; i += 256){
    int dr = i>>4; int j4 = (i&15)*4;
    float4 v = *(const float4*)(P.xconv + ((size_t)(s*DIC + dr))*L2 + pg*64 + j4);
    *(float4*)&smem[dr*68 + j4] = v;
  }
  __syncthreads();
  if (k == 0){
    float* ub = P.u_t + ((size_t)(s*L2) + pg*64)*DIC;
    for (int i = tid; i < 64*128; i += 256){
      int px2 = i>>7; int dd = i&127;
      ub[(size_t)px2*DIC + dd] = smem[dd*68 + px2];
    }
  }
  int px = tid & 63;
  int cgrp = __builtin_amdgcn_readfirstlane(tid >> 6);
  int c0 = cgrp*9;
  const float* wb = P.x_proj_w + (size_t)(k*36 + c0)*DIC;
  float acc[9];
  #pragma unroll
  for (int ci=0;ci<9;++ci) acc[ci]=0.f;
  for (int d=0; d<DIC; ++d){
    float xv = smem[d*68 + px];
    #pragma unroll
    for (int ci=0;ci<9;++ci) acc[ci] = fmaf(wb[ci*DIC+d], xv, acc[ci]);
  }
  __syncthreads();
  #pragma unroll
  for (int ci=0;ci<9;++ci) smem[(c0+ci)*68 + px] = acc[ci];
  __syncthreads();
  int d = tid & 127; int half = tid >> 7;
  float w0 = P.dt_proj_w[(k*DIC+d)*4+0], w1 = P.dt_proj_w[(k*DIC+d)*4+1];
  float w2 = P.dt_proj_w[(k*DIC+d)*4+2], w3 = P.dt_proj_w[(k*DIC+d)*4+3];
  float bb = P.dt_proj_b[k*DIC+d];
  float* dout = P.dtp + ((size_t)sk*L2 + pg*64)*DIC + d;
  for (int pp = half*32; pp < half*32+32; ++pp){
    float r0 = smem[0*68+pp], r1 = smem[1*68+pp], r2 = smem[2*68+pp], r3 = smem[3*68+pp];
    float val = fsoftplus(fmaf(w0,r0,fmaf(w1,r1,fmaf(w2,r2,fmaf(w3,r3,bb)))));
    dout[(size_t)pp*DIC] = val;
  }
  float* Bb = P.Bp + ((size_t)sk*L2 + pg*64)*NST;
  float* Cb = P.Cp + ((size_t)sk*L2 + pg*64)*NST;
  for (int i = tid; i < 1024; i += 256){
    int pp = i>>4; int n = i&15;
    Bb[pp*NST + n] = smem[(4+n)*68 + pp];
    Cb[pp*NST + n] = smem[(20+n)*68 + pp];
  }
}

__device__ __forceinline__ void p10_scan_part(int vb, int tid, const MegaP& P){
  int chp = vb & 15; int sk = vb >> 4;
  int k = sk & 3; int s = sk >> 2;
  int d = tid & 127; int ch = chp*2 + (tid>>7);
  float aco[16];
  {
    const float* ab = P.A_logs + (size_t)(k*DIC+d)*NST;
    #pragma unroll
    for (int n=0;n<16;++n) aco[n] = -LOG2E * fexp(ab[n]);
  }
  float h[16], Pr[16];
  #pragma unroll
  for (int n=0;n<16;++n){ h[n]=0.f; Pr[n]=1.f; }
  const float* db = P.dtp + (size_t)sk*L2*DIC + d;
  const float* ub = P.u_t + (size_t)s*L2*DIC + d;
  const float* Bb = P.Bp + (size_t)sk*L2*NST;
  StepB cur = loadB(db, ub, Bb, scan_pix32(ch, 0, k));
  #pragma unroll 4
  for (int j=0;j<32;++j){
    StepB nxt;
    if (j < 31) nxt = loadB(db, ub, Bb, scan_pix32(ch, j+1, k));
    float tv = cur.dtv*cur.uv;
    #define PSTEP(NI, BV) { float a_ = __builtin_amdgcn_exp2f(cur.dtv*aco[NI]); \
      h[NI] = fmaf(a_, h[NI], tv*(BV)); Pr[NI] *= a_; }
    PSTEP(0,cur.B0.x) PSTEP(1,cur.B0.y) PSTEP(2,cur.B0.z) PSTEP(3,cur.B0.w)
    PSTEP(4,cur.B1.x) PSTEP(5,cur.B1.y) PSTEP(6,cur.B1.z) PSTEP(7,cur.B1.w)
    PSTEP(8,cur.B2.x) PSTEP(9,cur.B2.y) PSTEP(10,cur.B2.z) PSTEP(11,cur.B2.w)
    PSTEP(12,cur.B3.x) PSTEP(13,cur.B3.y) PSTEP(14,cur.B3.z) PSTEP(15,cur.B3.w)
    #undef PSTEP
    cur = nxt;
  }
  size_t base = ((size_t)(sk*NCH + ch)*DIC + d)*NST;
  #pragma unroll
  for (int q4=0;q4<4;++q4){
    *(float4*)(P.hend + base + q4*4)  = make_float4(h[q4*4],h[q4*4+1],h[q4*4+2],h[q4*4+3]);
    *(float4*)(P.prodA + base + q4*4) = make_float4(Pr[q4*4],Pr[q4*4+1],Pr[q4*4+2],Pr[q4*4+3]);
  }
}

__device__ __forceinline__ void p11_scan_fix(int vb, int tid, const MegaP& P){
  int t = vb*256 + tid;
  int n = t & 15; int d = (t>>4) & 127; int sk = t >> 11;
  float H = 0.f;
  for (int ch=0; ch<NCH; ++ch){
    size_t idx = ((size_t)(sk*NCH + ch)*DIC + d)*NST + n;
    float pa = P.prodA[idx];
    float he = P.hend[idx];
    P.prodA[idx] = H;
    H = fmaf(pa, H, he);
  }
}

__device__ __forceinline__ void p12_scan_y(int vb, int tid, const MegaP& P){
  int chp = vb & 15; int sk = vb >> 4;
  int k = sk & 3; int s = sk >> 2;
  int d = tid & 127; int ch = chp*2 + (tid>>7);
  float aco[16];
  {
    const float* ab = P.A_logs + (size_t)(k*DIC+d)*NST;
    #pragma unroll
    for (int n=0;n<16;++n) aco[n] = -LOG2E * fexp(ab[n]);
  }
  float Dv = P.Ds[k*DIC+d];
  float h[16];
  size_t hbase = ((size_t)(sk*NCH + ch)*DIC + d)*NST;
  #pragma unroll
  for (int q4=0;q4<4;++q4){
    float4 hv = *(const float4*)(P.prodA + hbase + q4*4);
    h[q4*4]=hv.x; h[q4*4+1]=hv.y; h[q4*4+2]=hv.z; h[q4*4+3]=hv.w;
  }
  const float* db = P.dtp + (size_t)sk*L2*DIC + d;
  const float* ub = P.u_t + (size_t)s*L2*DIC + d;
  const float* Bb = P.Bp + (size_t)sk*L2*NST;
  const float* Cb = P.Cp + (size_t)sk*L2*NST;
  float* yb = P.ys_t + (size_t)sk*L2*DIC + d;
  int pcur = scan_pix32(ch, 0, k);
  StepB cur = loadB(db, ub, Bb, pcur);
  float4 Cc0 = *(const float4*)(Cb + pcur*NST);
  float4 Cc1 = *(const float4*)(Cb + pcur*NST + 4);
  float4 Cc2 = *(const float4*)(Cb + pcur*NST + 8);
  float4 Cc3 = *(const float4*)(Cb + pcur*NST + 12);
  #pragma unroll 4
  for (int j=0;j<32;++j){
    StepB nxt; float4 Cn0, Cn1, Cn2, Cn3; int pn = pcur;
    if (j < 31){
      pn = scan_pix32(ch, j+1, k);
      nxt = loadB(db, ub, Bb, pn);
      Cn0 = *(const float4*)(Cb + pn*NST);
      Cn1 = *(const float4*)(Cb + pn*NST + 4);
      Cn2 = *(const float4*)(Cb + pn*NST + 8);
      Cn3 = *(const float4*)(Cb + pn*NST + 12);
    }
    float tv = cur.dtv*cur.uv;
    float y0=0.f, y1=0.f, y2=0.f, y3=0.f;
    #define YSTEP(NI, BV, CV, YA) { float a_ = __builtin_amdgcn_exp2f(cur.dtv*aco[NI]); \
      h[NI] = fmaf(a_, h[NI], tv*(BV)); YA = fmaf(h[NI], (CV), YA); }
    YSTEP(0,cur.B0.x,Cc0.x,y0) YSTEP(1,cur.B0.y,Cc0.y,y1) YSTEP(2,cur.B0.z,Cc0.z,y2) YSTEP(3,cur.B0.w,Cc0.w,y3)
    YSTEP(4,cur.B1.x,Cc1.x,y0) YSTEP(5,cur.B1.y,Cc1.y,y1) YSTEP(6,cur.B1.z,Cc1.z,y2) YSTEP(7,cur.B1.w,Cc1.w,y3)
    YSTEP(8,cur.B2.x,Cc2.x,y0) YSTEP(9,cur.B2.y,Cc2.y,y1) YSTEP(10,cur.B2.z,Cc2.z,y2) YSTEP(11,cur.B2.w,Cc2.w,y3)
    YSTEP(12,cur.B3.x,Cc3.x,y0) YSTEP(13,cur.B3.y,Cc3.y,y1) YSTEP(14,cur.B3.z,Cc3.z,y2) YSTEP(15,cur.B3.w,Cc3.w,y3)
    #undef YSTEP
    yb[(size_t)pcur*DIC] = fmaf(cur.uv, Dv, (y0+y1)+(y2+y3));
    cur = nxt; Cc0 = Cn0; Cc1 = Cn1; Cc2 = Cn2; Cc3 = Cn3; pcur = pn;
  }
}

__device__ __forceinline__ void p13_combine(int vb, int tid, const MegaP& P, float* yt){
  int s = vb >> 6; int pg = vb & 63;
  int wv = __builtin_amdgcn_readfirstlane(tid>>6); int lane = tid&63;
  int d0 = lane, d1 = lane+64;
  for (int i=0;i<4;++i){
    int px = i*4 + wv; int p = pg*16 + px;
    const float* yb = P.ys_t + ((size_t)(s*4)*L2 + p)*DIC;
    float ya = yb[d0] + yb[(size_t)L2*DIC + d0] + yb[(size_t)2*L2*DIC + d0] + yb[(size_t)3*L2*DIC + d0];
    float yc = yb[d1] + yb[(size_t)L2*DIC + d1] + yb[(size_t)2*L2*DIC + d1] + yb[(size_t)3*L2*DIC + d1];
    float sm = ya+yc, sq = ya*ya+yc*yc;
    for (int m=1;m<64;m<<=1){ sm+=__shfl_xor(sm,m,64); sq+=__shfl_xor(sq,m,64); }
    float mean = sm*(1.f/128.f); float var = sq*(1.f/128.f)-mean*mean;
    float rs = rsqrtf(var + 1e-5f);
    float yn0 = (ya-mean)*rs*P.out_norm_g[d0] + P.out_norm_b[d0];
    float yn1 = (yc-mean)*rs*P.out_norm_g[d1] + P.out_norm_b[d1];
    float zv0 = P.z_t[((size_t)s*DIC+d0)*L2 + p];
    float zv1 = P.z_t[((size_t)s*DIC+d1)*L2 + p];
    yt[d0*17 + px] = yn0 * fsilu(zv0);
    yt[d1*17 + px] = yn1 * fsilu(zv1);
  }
  __syncthreads();
  int px = tid & 15; int cgp = tid >> 4;   // per-lane (NOT readfirstlane — wave=64)
  int c0 = cgp*4;
  float a0=0.f,a1=0.f,a2=0.f,a3=0.f;
  for (int d=0; d<DIC; ++d){
    float yv = yt[d*17 + px];
    a0 = fmaf(P.out_proj_w[(c0+0)*DIC + d], yv, a0);
    a1 = fmaf(P.out_proj_w[(c0+1)*DIC + d], yv, a1);
    a2 = fmaf(P.out_proj_w[(c0+2)*DIC + d], yv, a2);
    a3 = fmaf(P.out_proj_w[(c0+3)*DIC + d], yv, a3);
  }
  int p = pg*16 + px;
  size_t base = ((size_t)s*CCH + c0)*L2 + p;
  P.xv[base]      = P.x_cmaj[base]      + a0;
  P.xv[base+L2]   = P.x_cmaj[base+L2]   + a1;
  P.xv[base+2*L2] = P.x_cmaj[base+2*L2] + a2;
  P.xv[base+3*L2] = P.x_cmaj[base+3*L2] + a3;
}

__device__ __forceinline__ void p14_mlp(int vb, int tid, const MegaP& P, float* smem){
  float* xt = smem;          // 64*33 = 2112
  float* ts = smem + 2112;   // 32*65 = 2080
  int s = vb >> 5; int p0 = (vb & 31)*32;
  int px = tid & 31; int cgp = tid >> 5;   // per-lane
  #pragma unroll
  for (int j=0;j<8;++j){
    int c = cgp*8 + j;
    xt[c*33 + px] = P.xv[((size_t)s*CCH + c)*L2 + p0 + px];
  }
  __syncthreads();
  float sm=0.f, sq=0.f;
  for (int c=0;c<64;++c){ float v = xt[c*33+px]; sm+=v; sq+=v*v; }
  float mean = sm*(1.f/64.f);
  float rs = rsqrtf(sq*(1.f/64.f) - mean*mean + 1e-5f);
  int o0 = cgp*8;
  float t[8];
  #pragma unroll
  for (int oi=0;oi<8;++oi) t[oi] = P.fc1_b[o0+oi];
  for (int c=0;c<64;++c){
    float xn = (xt[c*33+px]-mean)*rs*P.ln2_g[c] + P.ln2_b[c];
    #pragma unroll
    for (int oi=0;oi<8;++oi) t[oi] = fmaf(xn, P.fc1_w[(o0+oi)*64 + c], t[oi]);
  }
  #pragma unroll
  for (int oi=0;oi<8;++oi) ts[px*65 + o0+oi] = fgelu(t[oi]);
  __syncthreads();
  int c0 = cgp*8;
  float acc[8];
  #pragma unroll
  for (int ci=0;ci<8;++ci) acc[ci] = xt[(c0+ci)*33+px] + P.fc2_b[c0+ci];
  for (int o=0;o<64;++o){
    float tv = ts[px*65 + o];
    #pragma unroll
    for (int ci=0;ci<8;++ci) acc[ci] = fmaf(tv, P.fc2_w[(c0+ci)*64 + o], acc[ci]);
  }
  #pragma unroll
  for (int ci=0;ci<8;++ci) P.out[((size_t)s*CCH + c0+ci)*L2 + p0 + px] = acc[ci];
}

// ===== cooperative mega-kernel =====
__global__ __launch_bounds__(256,2) void k_mega(MegaP P){
  cg::grid_group grd = cg::this_grid();
  __shared__ float smem[8704];
  const int tid = threadIdx.x;
  for (int vb = blockIdx.x; vb < 96; vb += gridDim.x){ p0_ln2d(vb, tid, P, smem); __syncthreads(); }
  grd.sync();
  for (int vb = blockIdx.x; vb < 6*C3; vb += gridDim.x)
    gnact_body(vb, tid, P.x3c, P.psum1, P.psq1, P.gn1_g, P.gn1_b, C3, 1.f/(C3*L2), 1e-5f, P.xact1);
  grd.sync();
  for (int vb = blockIdx.x; vb < 1536; vb += gridDim.x) p2_conv1(vb, tid, P);
  grd.sync();
  for (int vb = blockIdx.x; vb < 384; vb += gridDim.x){ p3_reduce1(vb, tid, P, smem); __syncthreads(); }
  grd.sync();
  for (int vb = blockIdx.x; vb < 6*CCH; vb += gridDim.x)
    gnact_body(vb, tid, P.h1, P.psum2, P.psq2, P.gn2_g, P.gn2_b, CCH, 1.f/(CCH*L2), 1e-5f, P.xact2);
  grd.sync();
  for (int vb = blockIdx.x; vb < 576; vb += gridDim.x) p5_conv2(vb, tid, P);
  grd.sync();
  for (int vb = blockIdx.x; vb < 384; vb += gridDim.x) p6_reduce2(vb, tid, P);
  grd.sync();
  for (int vb = blockIdx.x; vb < 384; vb += gridDim.x){ p7_ln1_inproj(vb, tid, P, smem); __syncthreads(); }
  grd.sync();
  for (int vb = blockIdx.x; vb < 768; vb += gridDim.x) p8_dwconv(vb, tid, P);
  grd.sync();
  for (int vb = blockIdx.x; vb < 384; vb += gridDim.x){ p9_xproj_dt(vb, tid, P, smem); __syncthreads(); }
  grd.sync();
  for (int vb = blockIdx.x; vb < 384; vb += gridDim.x) p10_scan_part(vb, tid, P);
  grd.sync();
  for (int vb = blockIdx.x; vb < 192; vb += gridDim.x) p11_scan_fix(vb, tid, P);
  grd.sync();
  for (int vb = blockIdx.x; vb < 384; vb += gridDim.x) p12_scan_y(vb, tid, P);
  grd.sync();
  for (int vb = blockIdx.x; vb < 384; vb += gridDim.x){ p13_combine(vb, tid, P, smem); __syncthreads(); }
  grd.sync();
  for (int vb = blockIdx.x; vb < 192; vb += gridDim.x){ p14_mlp(vb, tid, P, smem); __syncthreads(); }
}

// ===== fallback per-phase wrapper kernels =====
__global__ __launch_bounds__(256) void k_p0(MegaP P){
  __shared__ float smem[512]; p0_ln2d(blockIdx.x, threadIdx.x, P, smem);
}
__global__ __launch_bounds__(256) void k_p1(MegaP P){
  gnact_body(blockIdx.x, threadIdx.x, P.x3c, P.psum1, P.psq1, P.gn1_g, P.gn1_b, C3, 1.f/(C3*L2), 1e-5f, P.xact1);
}
__global__ __launch_bounds__(256) void k_p2(MegaP P){ p2_conv1(blockIdx.x, threadIdx.x, P); }
__global__ __launch_bounds__(256) void k_p3(MegaP P){
  __shared__ float smem[8]; p3_reduce1(blockIdx.x, threadIdx.x, P, smem);
}
__global__ __launch_bounds__(256) void k_p4(MegaP P){
  gnact_body(blockIdx.x, threadIdx.x, P.h1, P.psum2, P.psq2, P.gn2_g, P.gn2_b, CCH, 1.f/(CCH*L2), 1e-5f, P.xact2);
}
__global__ __launch_bounds__(256) void k_p5(MegaP P){ p5_conv2(blockIdx.x, threadIdx.x, P); }
__global__ __launch_bounds__(256) void k_p6(MegaP P){ p6_reduce2(blockIdx.x, threadIdx.x, P); }
__global__ __launch_bounds__(256) void k_p7(MegaP P){
  __shared__ float smem[64*65]; p7_ln1_inproj(blockIdx.x, threadIdx.x, P, smem);
}
__global__ __launch_bounds__(256) void k_p8(MegaP P){ p8_dwconv(blockIdx.x, threadIdx.x, P); }
__global__ __launch_bounds__(256) void k_p9(MegaP P){
  __shared__ float smem[8704]; p9_xproj_dt(blockIdx.x, threadIdx.x, P, smem);
}
__global__ __launch_bounds__(256,2) void k_p10(MegaP P){ p10_scan_part(blockIdx.x, threadIdx.x, P); }
__global__ __launch_bounds__(256) void k_p11(MegaP P){ p11_scan_fix(blockIdx.x, threadIdx.x, P); }
__global__ __launch_bounds__(256,2) void k_p12(MegaP P){ p12_scan_y(blockIdx.x, threadIdx.x, P); }
__global__ __launch_bounds__(256) void k_p13(MegaP P){
  __shared__ float smem[128*17]; p13_combine(blockIdx.x, threadIdx.x, P, smem);
}
__global__ __launch_bounds__(256) void k_p14(MegaP P){
  __shared__ float smem[4192]; p14_mlp(blockIdx.x, threadIdx.x, P, smem);
}

extern "C" void kernel_launch(void* const* d_in, const int* in_sizes, int n_in,
                              void* d_out, int out_size, void* d_ws, size_t ws_size,
                              hipStream_t stream){
  (void)in_sizes; (void)n_in; (void)out_size; (void)ws_size;
  float* ws = (float*)d_ws;
  float* x3c    = ws;                       // 1,179,648
  float* xact1  = x3c    + 1179648;         // 1,253,376 (padded)
  float* h1     = xact1  + 1253376;         // 393,216
  float* xact2  = h1     + 393216;          // 417,792 (padded)
  float* xp     = xact2  + 417792;          // 393,216
  float* x_cmaj = xp     + 393216;          // 393,216
  float* z_t    = x_cmaj + 393216;          // 786,432
  float* xc     = z_t    + 786432;          // 786,432
  float* xconv  = xc     + 786432;          // 786,432
  float* hole   = xconv  + 786432;          // 884,736 (tail of prodA alias)
  float* dtp    = hole   + 884736;          // 3,145,728 (hosts conv1 partials first)
  float* ys_t   = dtp    + 3145728;         // 3,145,728 (hosts conv2 partials first)
  float* xv     = ys_t   + 3145728;         // 393,216
  float* statsb = xv     + 393216;          // 24 floats

  MegaP Pm;
  Pm.img = (const float*)d_in[0];  Pm.dz = (const float*)d_in[1];
  Pm.sg = (const float*)d_in[2];   Pm.norm_g = (const float*)d_in[3];
  Pm.norm_b = (const float*)d_in[4]; Pm.gn1_g = (const float*)d_in[5];
  Pm.gn1_b = (const float*)d_in[6]; Pm.conv1_w = (const float*)d_in[7];
  Pm.conv1_b = (const float*)d_in[8]; Pm.gn2_g = (const float*)d_in[9];
  Pm.gn2_b = (const float*)d_in[10]; Pm.conv2_w = (const float*)d_in[11];
  Pm.conv2_b = (const float*)d_in[12]; Pm.skip_w = (const float*)d_in[13];
  Pm.skip_b = (const float*)d_in[14]; Pm.ln1_g = (const float*)d_in[15];
  Pm.ln1_b = (const float*)d_in[16]; Pm.ln2_g = (const float*)d_in[17];
  Pm.ln2_b = (const float*)d_in[18]; Pm.in_proj_w = (const float*)d_in[19];
  Pm.dwconv_w = (const float*)d_in[20]; Pm.dwconv_b = (const float*)d_in[21];
  Pm.x_proj_w = (const float*)d_in[22]; Pm.dt_proj_w = (const float*)d_in[23];
  Pm.dt_proj_b = (const float*)d_in[24]; Pm.A_logs = (const float*)d_in[25];
  Pm.Ds = (const float*)d_in[26]; Pm.out_norm_g = (const float*)d_in[27];
  Pm.out_norm_b = (const float*)d_in[28]; Pm.out_proj_w = (const float*)d_in[29];
  Pm.fc1_w = (const float*)d_in[30]; Pm.fc1_b = (const float*)d_in[31];
  Pm.fc2_w = (const float*)d_in[32]; Pm.fc2_b = (const float*)d_in[33];

  Pm.x3c = x3c; Pm.xact1 = xact1; Pm.h1 = h1; Pm.xact2 = xact2; Pm.xp = xp;
  Pm.x_cmaj = x_cmaj; Pm.z_t = z_t; Pm.xc = xc; Pm.xconv = xconv;
  Pm.dtp = dtp; Pm.ys_t = ys_t; Pm.xv = xv;
  Pm.psum1 = statsb; Pm.psq1 = statsb+6; Pm.psum2 = statsb+12; Pm.psq2 = statsb+18;
  Pm.part1 = dtp;            // conv1 partials, consumed phase 3 < dtp write phase 9
  Pm.part2 = ys_t;           // conv2 partials, consumed phase 6 < ys_t write phase 12
  Pm.hend  = x3c;            // x3c last read phase 5; hend written phase 10
  Pm.prodA = xconv;          // xconv last read phase 9; prodA written phase 10 (spills into hole)
  Pm.u_t   = h1;             // h1/xact2 last read phases 4/5; u_t written phase 9
  Pm.Bp    = xp;             // xp last read phase 7
  Pm.Cp    = xc;             // xc last read phase 8
  Pm.out   = (float*)d_out;

  hipMemsetAsync(statsb, 0, 24*sizeof(float), stream);

  // try cooperative mega-kernel with runtime-validated grid; fall back to 15 dispatches
  hipError_t le = hipErrorUnknown;
  int dev = 0;
  if (hipGetDevice(&dev) == hipSuccess){
    int numCU = 0, maxB = 0;
    hipDeviceGetAttribute(&numCU, hipDeviceAttributeMultiprocessorCount, dev);
    hipError_t oe = hipOccupancyMaxActiveBlocksPerMultiprocessor(&maxB, k_mega, 256, 0);
    if (oe == hipSuccess && maxB > 0 && numCU > 0){
      int grid = maxB * numCU; if (grid > 512) grid = 512;
      if (grid >= 64){
        void* args[] = { (void*)&Pm };
        le = hipLaunchCooperativeKernel(k_mega, dim3(grid), dim3(256), args, 0u, stream);
      }
    }
  }
  if (le != hipSuccess){
    k_p0 <<<96,   256, 0, stream>>>(Pm);
    k_p1 <<<6*C3, 256, 0, stream>>>(Pm);
    k_p2 <<<1536, 256, 0, stream>>>(Pm);
    k_p3 <<<384,  256, 0, stream>>>(Pm);
    k_p4 <<<6*CCH,256, 0, stream>>>(Pm);
    k_p5 <<<576,  256, 0, stream>>>(Pm);
    k_p6 <<<384,  256, 0, stream>>>(Pm);
    k_p7 <<<384,  256, 0, stream>>>(Pm);
    k_p8 <<<768,  256, 0, stream>>>(Pm);
    k_p9 <<<384,  256, 0, stream>>>(Pm);
    k_p10<<<384,  256, 0, stream>>>(Pm);
    k_p11<<<192,  256, 0, stream>>>(Pm);
    k_p12<<<384,  256, 0, stream>>>(Pm);
    k_p13<<<384,  256, 0, stream>>>(Pm);
    k_p14<<<192,  256, 0, stream>>>(Pm);
  }
}

// Round 11
// 308.606 us; speedup vs baseline: 2.7976x; 2.7976x over previous
//
#include <hip/hip_runtime.h>
#include <math.h>

// Problem dims
#define BL    6
#define CCH   64
#define C3    192
#define L2    1024
#define DIC   128
#define NST   16
#define K4    4
#define PSTR  1088   // padded plane stride: 34 rows * 32 cols
#define NCH   32     // scan chunks per sequence (32 steps each)

#define LOG2E 1.44269504088896340736f
#define LN2C  0.69314718055994530942f

__device__ __forceinline__ float fexp(float x){ return __builtin_amdgcn_exp2f(x*LOG2E); }
__device__ __forceinline__ float fsilu(float x){ return x / (1.f + fexp(-x)); }
__device__ __forceinline__ float fsoftplus(float x){
  if (x > 20.f) return x;
  return __builtin_amdgcn_logf(1.f + fexp(x)) * LN2C;
}
__device__ __forceinline__ float fgelu(float x){
  return 0.5f*x*(1.f + erff(x*0.70710678118654752440f));
}

// ---------------- p0: per-pixel LN of frames + concat; per-block GN1 partial sums
__global__ __launch_bounds__(256) void k_ln2d(const float* __restrict__ img,
    const float* __restrict__ dz, const float* __restrict__ sg,
    const float* __restrict__ g, const float* __restrict__ b, float* __restrict__ x3c,
    float* __restrict__ psum1, float* __restrict__ psq1){
  __shared__ float ps[4][64], pq[4][64];
  int s = blockIdx.x >> 4;
  int lane = threadIdx.x & 63;
  int cg = threadIdx.x >> 6;
  int p = ((blockIdx.x & 15) << 6) + lane;
  int bsmp = s/3;
  const float* fr = img + (size_t)s*CCH*L2;
  float vals[16]; float sm=0.f, sq=0.f;
  #pragma unroll
  for (int j=0;j<16;++j){
    int c = cg*16+j;
    float v = fr[c*L2+p];
    vals[j]=v; sm+=v; sq+=v*v;
  }
  ps[cg][lane]=sm; pq[cg][lane]=sq;
  __syncthreads();
  sm = ps[0][lane]+ps[1][lane]+ps[2][lane]+ps[3][lane];
  sq = pq[0][lane]+pq[1][lane]+pq[2][lane]+pq[3][lane];
  float mean = sm*(1.f/CCH); float var = sq*(1.f/CCH) - mean*mean;
  float rs = rsqrtf(var + 1e-6f);
  float* o = x3c + (size_t)s*C3*L2;
  const float* dzp = dz + (size_t)bsmp*CCH*L2;
  const float* sgp = sg + (size_t)bsmp*CCH*L2;
  float gsm=0.f, gsq=0.f;
  #pragma unroll
  for (int j=0;j<16;++j){
    int c = cg*16+j;
    float dzv = dzp[c*L2+p];
    float nv  = (vals[j]-mean)*rs*g[c] + b[c];
    float sgv = sgp[c*L2+p];
    o[c*L2+p] = dzv;
    o[(CCH+c)*L2+p] = nv;
    o[(2*CCH+c)*L2+p] = sgv;
    gsm += dzv+nv+sgv; gsq += dzv*dzv+nv*nv+sgv*sgv;
  }
  for (int m=1;m<64;m<<=1){ gsm+=__shfl_xor(gsm,m,64); gsq+=__shfl_xor(gsq,m,64); }
  __syncthreads();
  if (lane==0){ ps[cg][0]=gsm; pq[cg][0]=gsq; }
  __syncthreads();
  if (threadIdx.x==0){
    psum1[blockIdx.x] = ps[0][0]+ps[1][0]+ps[2][0]+ps[3][0];
    psq1 [blockIdx.x] = pq[0][0]+pq[1][0]+pq[2][0]+pq[3][0];
  }
}

// ---------------- GN act + SiLU from per-block partials (parts slots per sample), padded write
__global__ __launch_bounds__(256) void k_gnact_pad(const float* __restrict__ x,
    const float* __restrict__ psum, const float* __restrict__ psq,
    const float* __restrict__ g, const float* __restrict__ b,
    int ch, int parts, float inv_n, float eps, float* __restrict__ out){
  int bx = blockIdx.x;
  int s = bx / ch; int c = bx % ch;
  int tid = threadIdx.x;
  float sm=0.f, sq=0.f;
  for (int i=0;i<parts;++i){ sm += psum[s*parts+i]; sq += psq[s*parts+i]; }
  float mean = sm*inv_n;
  float var = sq*inv_n - mean*mean;
  float rs = rsqrtf(var + eps);
  float gc = g[c]*rs; float bc = b[c] - mean*rs*g[c];
  float4 v = *(const float4*)(x + (size_t)bx*1024 + tid*4);
  float4 o; o.x = fsilu(v.x*gc+bc); o.y = fsilu(v.y*gc+bc);
  o.z = fsilu(v.z*gc+bc); o.w = fsilu(v.w*gc+bc);
  float* pl = out + (size_t)bx*PSTR;
  *(float4*)(pl + 32 + tid*4) = o;
  float4 z4 = make_float4(0.f,0.f,0.f,0.f);
  if (tid < 8)  *(float4*)(pl + tid*4) = z4;
  else if (tid < 16) *(float4*)(pl + 1056 + (tid-8)*4) = z4;
}

// conv helpers
__device__ __forceinline__ void conv_row_acc(float4& a0, float4& a1, float4 mid, float lf, float rt,
    const float* wp0, const float* wp1){
  float w0=wp0[0], w1=wp0[1], w2=wp0[2];
  a0.x = fmaf(w0,lf,   fmaf(w1,mid.x, fmaf(w2,mid.y, a0.x)));
  a0.y = fmaf(w0,mid.x,fmaf(w1,mid.y, fmaf(w2,mid.z, a0.y)));
  a0.z = fmaf(w0,mid.y,fmaf(w1,mid.z, fmaf(w2,mid.w, a0.z)));
  a0.w = fmaf(w0,mid.z,fmaf(w1,mid.w, fmaf(w2,rt,    a0.w)));
  float v0=wp1[0], v1=wp1[1], v2=wp1[2];
  a1.x = fmaf(v0,lf,   fmaf(v1,mid.x, fmaf(v2,mid.y, a1.x)));
  a1.y = fmaf(v0,mid.x,fmaf(v1,mid.y, fmaf(v2,mid.z, a1.y)));
  a1.z = fmaf(v0,mid.y,fmaf(v1,mid.z, fmaf(v2,mid.w, a1.z)));
  a1.w = fmaf(v0,mid.z,fmaf(v1,mid.w, fmaf(v2,rt,    a1.w)));
}

__device__ __forceinline__ void conv_ci_body(float4 m0, float4 m1, float4 m2, int q,
    const float* wp0, const float* wp1, float4& a0, float4& a1){
  float lf0=__shfl_up(m0.w,1,64), rt0=__shfl_down(m0.x,1,64);
  float lf1=__shfl_up(m1.w,1,64), rt1=__shfl_down(m1.x,1,64);
  float lf2=__shfl_up(m2.w,1,64), rt2=__shfl_down(m2.x,1,64);
  if (q==0){ lf0=0.f; lf1=0.f; lf2=0.f; }
  if (q==7){ rt0=0.f; rt1=0.f; rt2=0.f; }
  conv_row_acc(a0,a1,m0,lf0,rt0, wp0+0, wp1+0);
  conv_row_acc(a0,a1,m1,lf1,rt1, wp0+3, wp1+3);
  conv_row_acc(a0,a1,m2,lf2,rt2, wp0+6, wp1+6);
}

// ---------------- conv1: 192ci -> 64co, split-K=8, padded input
__global__ __launch_bounds__(256) void k_conv1_split(const float* __restrict__ xact,
    const float* __restrict__ w, float* __restrict__ part){
  int bx = blockIdx.x; int kk = bx&7; int cop=(bx>>3)&31; int s=bx>>8;
  int co0 = cop*2, co1 = co0+1;
  int tid = threadIdx.x; int row = tid>>3; int q = tid&7; int col0 = q*4;
  float4 a0 = make_float4(0.f,0.f,0.f,0.f);
  float4 a1 = make_float4(0.f,0.f,0.f,0.f);
  int ci0 = kk*24;
  const float* pl = xact + ((size_t)s*C3 + ci0)*PSTR + row*32 + col0;
  const float* wp0 = w + (size_t)(co0*C3 + ci0)*9;
  const float* wp1 = w + (size_t)(co1*C3 + ci0)*9;
  float4 m0 = *(const float4*)(pl);
  float4 m1 = *(const float4*)(pl+32);
  float4 m2 = *(const float4*)(pl+64);
  #pragma unroll 2
  for (int i=0;i<24;++i){
    const float* pn = pl + (i<23 ? PSTR : 0);
    float4 n0 = *(const float4*)(pn);
    float4 n1 = *(const float4*)(pn+32);
    float4 n2 = *(const float4*)(pn+64);
    conv_ci_body(m0,m1,m2,q, wp0, wp1, a0, a1);
    wp0 += 9; wp1 += 9; pl = pn; m0=n0; m1=n1; m2=n2;
  }
  float* pp = part + (size_t)kk*(BL*CCH*L2) + ((size_t)s*CCH+co0)*L2 + row*32+col0;
  *(float4*)pp = a0;
  *(float4*)(pp+L2) = a1;
}

// ---------------- reduce conv1 partials + bias -> h1; per-block GN2 partial sums
__global__ __launch_bounds__(256) void k_reduce1(const float* __restrict__ part,
    const float* __restrict__ bias, float* __restrict__ h1,
    float* __restrict__ psum2, float* __restrict__ psq2){
  int co = blockIdx.x & 63; int s = blockIdx.x >> 6;
  size_t ofs = ((size_t)s*CCH+co)*L2 + threadIdx.x*4;
  const size_t stride = (size_t)BL*CCH*L2;
  float4 acc = *(const float4*)(part + ofs);
  #pragma unroll
  for (int kk=1;kk<8;++kk){
    float4 r = *(const float4*)(part + (size_t)kk*stride + ofs);
    acc.x += r.x; acc.y += r.y; acc.z += r.z; acc.w += r.w;
  }
  float bv = bias[co];
  acc.x += bv; acc.y += bv; acc.z += bv; acc.w += bv;
  *(float4*)(h1 + ofs) = acc;
  float sm = acc.x+acc.y+acc.z+acc.w;
  float sq = acc.x*acc.x+acc.y*acc.y+acc.z*acc.z+acc.w*acc.w;
  for (int m=1;m<64;m<<=1){ sm+=__shfl_xor(sm,m,64); sq+=__shfl_xor(sq,m,64); }
  __shared__ float s_sm[4], s_sq[4];
  int wv = threadIdx.x>>6;
  if ((threadIdx.x&63)==0){ s_sm[wv]=sm; s_sq[wv]=sq; }
  __syncthreads();
  if (threadIdx.x==0){
    psum2[blockIdx.x] = s_sm[0]+s_sm[1]+s_sm[2]+s_sm[3];
    psq2 [blockIdx.x] = s_sq[0]+s_sq[1]+s_sq[2]+s_sq[3];
  }
}

// ---------------- conv2 (roles 0/1 = 32ci each) + skip 1x1 (role 2)
__global__ __launch_bounds__(256) void k_conv2_split(const float* __restrict__ xact2,
    const float* __restrict__ x3c, const float* __restrict__ w2,
    const float* __restrict__ wsk, float* __restrict__ part){
  int t = blockIdx.x; int role = t % 3; t /= 3;
  int cop = t & 31; int s = t >> 5;
  int co0 = cop*2, co1 = co0+1;
  int tid = threadIdx.x; int row = tid>>3; int q = tid&7; int col0 = q*4;
  int p = row*32+col0;
  float4 a0 = make_float4(0.f,0.f,0.f,0.f);
  float4 a1 = make_float4(0.f,0.f,0.f,0.f);
  if (role < 2){
    int ci0 = role*32;
    const float* pl = xact2 + ((size_t)s*CCH + ci0)*PSTR + row*32 + col0;
    const float* wp0 = w2 + (size_t)(co0*CCH + ci0)*9;
    const float* wp1 = w2 + (size_t)(co1*CCH + ci0)*9;
    float4 m0 = *(const float4*)(pl);
    float4 m1 = *(const float4*)(pl+32);
    float4 m2 = *(const float4*)(pl+64);
    #pragma unroll 2
    for (int i=0;i<32;++i){
      const float* pn = pl + (i<31 ? PSTR : 0);
      float4 n0 = *(const float4*)(pn);
      float4 n1 = *(const float4*)(pn+32);
      float4 n2 = *(const float4*)(pn+64);
      conv_ci_body(m0,m1,m2,q, wp0, wp1, a0, a1);
      wp0 += 9; wp1 += 9; pl = pn; m0=n0; m1=n1; m2=n2;
    }
  } else {
    const float* x3 = x3c + (size_t)s*C3*L2 + p;
    #pragma unroll 4
    for (int ci=0; ci<C3; ++ci){
      float4 v = *(const float4*)(x3 + (size_t)ci*L2);
      float ws0 = wsk[co0*C3+ci], ws1 = wsk[co1*C3+ci];
      a0.x = fmaf(ws0,v.x,a0.x); a0.y = fmaf(ws0,v.y,a0.y); a0.z = fmaf(ws0,v.z,a0.z); a0.w = fmaf(ws0,v.w,a0.w);
      a1.x = fmaf(ws1,v.x,a1.x); a1.y = fmaf(ws1,v.y,a1.y); a1.z = fmaf(ws1,v.z,a1.z); a1.w = fmaf(ws1,v.w,a1.w);
    }
  }
  float* pp = part + (size_t)role*(BL*CCH*L2) + ((size_t)s*CCH+co0)*L2 + p;
  *(float4*)pp = a0;
  *(float4*)(pp+L2) = a1;
}

__global__ __launch_bounds__(256) void k_reduce2(const float* __restrict__ part,
    const float* __restrict__ b2, const float* __restrict__ bsk,
    float* __restrict__ xp, float* __restrict__ x_cmaj){
  int co = blockIdx.x & 63; int s = blockIdx.x >> 6;
  int p = threadIdx.x*4;
  size_t ofs = ((size_t)s*CCH+co)*L2 + p;
  const size_t stride = (size_t)BL*CCH*L2;
  float4 r0 = *(const float4*)(part + ofs);
  float4 r1 = *(const float4*)(part + stride + ofs);
  float4 r2 = *(const float4*)(part + 2*stride + ofs);
  float bv = b2[co]+bsk[co];
  float4 o;
  o.x = r0.x+r1.x+r2.x+bv;
  o.y = r0.y+r1.y+r2.y+bv;
  o.z = r0.z+r1.z+r2.z+bv;
  o.w = r0.w+r1.w+r2.w+bv;
  *(float4*)(x_cmaj + ofs) = o;
  float* xpb = xp + ((size_t)s*L2 + p)*CCH + co;
  xpb[0] = o.x; xpb[CCH] = o.y; xpb[2*CCH] = o.z; xpb[3*CCH] = o.w;
}

// ---------------- ln1 + in_proj, split-o
__global__ __launch_bounds__(256) void k_ln1_inproj(const float* __restrict__ xp,
    const float* __restrict__ g, const float* __restrict__ b, const float* __restrict__ W,
    float* __restrict__ xc, float* __restrict__ z_t){
  __shared__ float xn_s[64*65];
  int bx = blockIdx.x; int oq = bx & 3; int pg = (bx>>2)&15; int s = bx>>6;
  int p0 = pg*64;
  int tid = threadIdx.x; int wv = __builtin_amdgcn_readfirstlane(tid>>6); int lane = tid&63;
  for (int j=0;j<16;++j){
    int pl = wv*16 + j; int p = p0 + pl;
    float v = xp[((size_t)s*L2 + p)*CCH + lane];
    float sm = v, sq = v*v;
    for (int m=1;m<64;m<<=1){ sm += __shfl_xor(sm,m,64); sq += __shfl_xor(sq,m,64); }
    float mean = sm*(1.f/64.f); float var = sq*(1.f/64.f) - mean*mean;
    float rs = rsqrtf(var + 1e-5f);
    xn_s[pl*65 + lane] = (v-mean)*rs*g[lane] + b[lane];
  }
  __syncthreads();
  int px_l = tid & 63;
  int og = __builtin_amdgcn_readfirstlane(tid >> 6);
  int o0 = oq*64 + og*16;
  float acc[16];
  #pragma unroll
  for (int oi=0;oi<16;++oi) acc[oi]=0.f;
  for (int c=0;c<64;++c){
    float xv = xn_s[px_l*65 + c];
    #pragma unroll
    for (int oi=0;oi<16;++oi) acc[oi] = fmaf(W[(o0+oi)*64 + c], xv, acc[oi]);
  }
  int p = p0 + px_l;
  if (oq < 2){
    #pragma unroll
    for (int oi=0;oi<16;++oi) xc[((size_t)s*DIC + o0 + oi)*L2 + p] = acc[oi];
  } else {
    #pragma unroll
    for (int oi=0;oi<16;++oi) z_t[((size_t)s*DIC + (o0-128) + oi)*L2 + p] = acc[oi];
  }
}

// ---------------- depthwise 3x3 + SiLU
__global__ __launch_bounds__(256) void k_dwconv(const float* __restrict__ xc,
    const float* __restrict__ w, const float* __restrict__ bias, float* __restrict__ xconv){
  int bx = blockIdx.x; int dch = bx & 127; int s = bx >> 7;
  int tid = threadIdx.x; int row = tid>>3; int q = tid&7; int col0 = q*4;
  const float* xr = xc + ((size_t)s*DIC+dch)*L2;
  const float* wp = w + dch*9;
  float bv = bias[dch];
  float4 acc = make_float4(bv,bv,bv,bv);
  #pragma unroll
  for (int dy=-1;dy<=1;++dy){
    int r = row+dy;
    float4 mid = make_float4(0.f,0.f,0.f,0.f);
    if (0<=r && r<32) mid = *(const float4*)(xr + r*32 + col0);
    float lf = __shfl_up(mid.w,1,64); if(q==0) lf=0.f;
    float rt = __shfl_down(mid.x,1,64); if(q==7) rt=0.f;
    float w0=wp[(dy+1)*3], w1=wp[(dy+1)*3+1], w2=wp[(dy+1)*3+2];
    acc.x = fmaf(w0,lf,   fmaf(w1,mid.x, fmaf(w2,mid.y, acc.x)));
    acc.y = fmaf(w0,mid.x,fmaf(w1,mid.y, fmaf(w2,mid.z, acc.y)));
    acc.z = fmaf(w0,mid.y,fmaf(w1,mid.z, fmaf(w2,mid.w, acc.z)));
    acc.w = fmaf(w0,mid.z,fmaf(w1,mid.w, fmaf(w2,rt,    acc.w)));
  }
  acc.x = fsilu(acc.x); acc.y = fsilu(acc.y); acc.z = fsilu(acc.z); acc.w = fsilu(acc.w);
  *(float4*)(xconv + ((size_t)s*DIC+dch)*L2 + row*32+col0) = acc;
}

// ---------------- fused x_proj + dt_proj/softplus + B/C + u_t transpose (k==0)
__global__ __launch_bounds__(256) void k_xproj_dt(const float* __restrict__ xconv,
    const float* __restrict__ W, const float* __restrict__ dtw, const float* __restrict__ dtb,
    float* __restrict__ dtp, float* __restrict__ Bp, float* __restrict__ Cp,
    float* __restrict__ u_t){
  __shared__ float smem[128*68];
  int bx = blockIdx.x; int pg = bx & 15; int sk = bx >> 4;
  int k = sk & 3; int s = sk >> 2;
  int tid = threadIdx.x;
  for (int i = tid; i < 128*16; i += 256){
    int dr = i>>4; int j4 = (i&15)*4;
    float4 v = *(const float4*)(xconv + ((size_t)(s*DIC + dr))*L2 + pg*64 + j4);
    *(float4*)&smem[dr*68 + j4] = v;
  }
  __syncthreads();
  if (k == 0){
    float* ub = u_t + ((size_t)(s*L2) + pg*64)*DIC;
    for (int i = tid; i < 64*128; i += 256){
      int px2 = i>>7; int dd = i&127;
      ub[(size_t)px2*DIC + dd] = smem[dd*68 + px2];
    }
  }
  int px = tid & 63;
  int cgrp = __builtin_amdgcn_readfirstlane(tid >> 6);
  int c0 = cgrp*9;
  const float* wb = W + (size_t)(k*36 + c0)*DIC;
  float acc[9];
  #pragma unroll
  for (int ci=0;ci<9;++ci) acc[ci]=0.f;
  for (int d=0; d<DIC; ++d){
    float xv = smem[d*68 + px];
    #pragma unroll
    for (int ci=0;ci<9;++ci) acc[ci] = fmaf(wb[ci*DIC+d], xv, acc[ci]);
  }
  __syncthreads();
  #pragma unroll
  for (int ci=0;ci<9;++ci) smem[(c0+ci)*68 + px] = acc[ci];
  __syncthreads();
  int d = tid & 127; int half = tid >> 7;
  float w0 = dtw[(k*DIC+d)*4+0], w1 = dtw[(k*DIC+d)*4+1];
  float w2 = dtw[(k*DIC+d)*4+2], w3 = dtw[(k*DIC+d)*4+3];
  float bb = dtb[k*DIC+d];
  float* dout = dtp + ((size_t)sk*L2 + pg*64)*DIC + d;
  for (int pp = half*32; pp < half*32+32; ++pp){
    float r0 = smem[0*68+pp], r1 = smem[1*68+pp], r2 = smem[2*68+pp], r3 = smem[3*68+pp];
    float val = fsoftplus(fmaf(w0,r0,fmaf(w1,r1,fmaf(w2,r2,fmaf(w3,r3,bb)))));
    dout[(size_t)pp*DIC] = val;
  }
  float* Bb = Bp + ((size_t)sk*L2 + pg*64)*NST;
  float* Cb = Cp + ((size_t)sk*L2 + pg*64)*NST;
  for (int i = tid; i < 1024; i += 256){
    int pp = i>>4; int n = i&15;
    Bb[pp*NST + n] = smem[(4+n)*68 + pp];
    Cb[pp*NST + n] = smem[(20+n)*68 + pp];
  }
}

// scan pixel for direction k, chunk ch (32 steps), step j
__device__ __forceinline__ int scan_pix32(int ch, int j, int k){
  if (k==0) return ch*32 + j;
  if (k==1) return j*32 + ch;
  if (k==2) return 1023 - (ch*32 + j);
  return 1023 - (j*32 + ch);
}

struct StepB { float dtv, uv; float4 B0,B1,B2,B3; };
__device__ __forceinline__ StepB loadB(const float* db, const float* ub, const float* Bb, int p){
  StepB r;
  r.dtv = db[(size_t)p*DIC]; r.uv = ub[(size_t)p*DIC];
  const float* bp = Bb + p*NST;
  r.B0 = *(const float4*)bp; r.B1 = *(const float4*)(bp+4);
  r.B2 = *(const float4*)(bp+8); r.B3 = *(const float4*)(bp+12);
  return r;
}

// ======== Selective scan: 32 chunks x 32 steps, thread-per-d, manual prefetch ========
__global__ __launch_bounds__(256,2) void k_scan_part3(const float* __restrict__ dtp,
    const float* __restrict__ u_t, const float* __restrict__ Bp,
    const float* __restrict__ A_logs, float* __restrict__ hend, float* __restrict__ prodA){
  int bx = blockIdx.x; int chp = bx & 15; int sk = bx >> 4;
  int k = sk & 3; int s = sk >> 2;
  int tid = threadIdx.x; int d = tid & 127; int ch = chp*2 + (tid>>7);
  float aco[16];
  {
    const float* ab = A_logs + (size_t)(k*DIC+d)*NST;
    #pragma unroll
    for (int n=0;n<16;++n) aco[n] = -LOG2E * fexp(ab[n]);
  }
  float h[16], Pr[16];
  #pragma unroll
  for (int n=0;n<16;++n){ h[n]=0.f; Pr[n]=1.f; }
  const float* db = dtp + (size_t)sk*L2*DIC + d;
  const float* ub = u_t + (size_t)s*L2*DIC + d;
  const float* Bb = Bp + (size_t)sk*L2*NST;
  StepB cur = loadB(db, ub, Bb, scan_pix32(ch, 0, k));
  #pragma unroll 4
  for (int j=0;j<32;++j){
    StepB nxt;
    if (j < 31) nxt = loadB(db, ub, Bb, scan_pix32(ch, j+1, k));
    float tv = cur.dtv*cur.uv;
    #define PSTEP(NI, BV) { float a_ = __builtin_amdgcn_exp2f(cur.dtv*aco[NI]); \
      h[NI] = fmaf(a_, h[NI], tv*(BV)); Pr[NI] *= a_; }
    PSTEP(0,cur.B0.x) PSTEP(1,cur.B0.y) PSTEP(2,cur.B0.z) PSTEP(3,cur.B0.w)
    PSTEP(4,cur.B1.x) PSTEP(5,cur.B1.y) PSTEP(6,cur.B1.z) PSTEP(7,cur.B1.w)
    PSTEP(8,cur.B2.x) PSTEP(9,cur.B2.y) PSTEP(10,cur.B2.z) PSTEP(11,cur.B2.w)
    PSTEP(12,cur.B3.x) PSTEP(13,cur.B3.y) PSTEP(14,cur.B3.z) PSTEP(15,cur.B3.w)
    #undef PSTEP
    cur = nxt;
  }
  size_t base = ((size_t)(sk*NCH + ch)*DIC + d)*NST;
  #pragma unroll
  for (int q4=0;q4<4;++q4){
    *(float4*)(hend + base + q4*4)  = make_float4(h[q4*4],h[q4*4+1],h[q4*4+2],h[q4*4+3]);
    *(float4*)(prodA + base + q4*4) = make_float4(Pr[q4*4],Pr[q4*4+1],Pr[q4*4+2],Pr[q4*4+3]);
  }
}

__global__ __launch_bounds__(256) void k_scan_fix3(const float* __restrict__ hend,
    float* prodA_Hin){
  int t = blockIdx.x*256 + threadIdx.x;
  int n = t & 15; int d = (t>>4) & 127; int sk = t >> 11;
  float H = 0.f;
  for (int ch=0; ch<NCH; ++ch){
    size_t idx = ((size_t)(sk*NCH + ch)*DIC + d)*NST + n;
    float pa = prodA_Hin[idx];
    float he = hend[idx];
    prodA_Hin[idx] = H;
    H = fmaf(pa, H, he);
  }
}

__global__ __launch_bounds__(256,2) void k_scan_y3(const float* __restrict__ dtp,
    const float* __restrict__ u_t, const float* __restrict__ Bp, const float* __restrict__ Cp,
    const float* __restrict__ A_logs, const float* __restrict__ Ds,
    const float* __restrict__ Hin, float* __restrict__ ys_t){
  int bx = blockIdx.x; int chp = bx & 15; int sk = bx >> 4;
  int k = sk & 3; int s = sk >> 2;
  int tid = threadIdx.x; int d = tid & 127; int ch = chp*2 + (tid>>7);
  float aco[16];
  {
    const float* ab = A_logs + (size_t)(k*DIC+d)*NST;
    #pragma unroll
    for (int n=0;n<16;++n) aco[n] = -LOG2E * fexp(ab[n]);
  }
  float Dv = Ds[k*DIC+d];
  float h[16];
  size_t hbase = ((size_t)(sk*NCH + ch)*DIC + d)*NST;
  #pragma unroll
  for (int q4=0;q4<4;++q4){
    float4 hv = *(const float4*)(Hin + hbase + q4*4);
    h[q4*4]=hv.x; h[q4*4+1]=hv.y; h[q4*4+2]=hv.z; h[q4*4+3]=hv.w;
  }
  const float* db = dtp + (size_t)sk*L2*DIC + d;
  const float* ub = u_t + (size_t)s*L2*DIC + d;
  const float* Bb = Bp + (size_t)sk*L2*NST;
  const float* Cb = Cp + (size_t)sk*L2*NST;
  float* yb = ys_t + (size_t)sk*L2*DIC + d;
  int pcur = scan_pix32(ch, 0, k);
  StepB cur = loadB(db, ub, Bb, pcur);
  float4 Cc0 = *(const float4*)(Cb + pcur*NST);
  float4 Cc1 = *(const float4*)(Cb + pcur*NST + 4);
  float4 Cc2 = *(const float4*)(Cb + pcur*NST + 8);
  float4 Cc3 = *(const float4*)(Cb + pcur*NST + 12);
  #pragma unroll 4
  for (int j=0;j<32;++j){
    StepB nxt; float4 Cn0, Cn1, Cn2, Cn3; int pn = pcur;
    if (j < 31){
      pn = scan_pix32(ch, j+1, k);
      nxt = loadB(db, ub, Bb, pn);
      Cn0 = *(const float4*)(Cb + pn*NST);
      Cn1 = *(const float4*)(Cb + pn*NST + 4);
      Cn2 = *(const float4*)(Cb + pn*NST + 8);
      Cn3 = *(const float4*)(Cb + pn*NST + 12);
    }
    float tv = cur.dtv*cur.uv;
    float y0=0.f, y1=0.f, y2=0.f, y3=0.f;
    #define YSTEP(NI, BV, CV, YA) { float a_ = __builtin_amdgcn_exp2f(cur.dtv*aco[NI]); \
      h[NI] = fmaf(a_, h[NI], tv*(BV)); YA = fmaf(h[NI], (CV), YA); }
    YSTEP(0,cur.B0.x,Cc0.x,y0) YSTEP(1,cur.B0.y,Cc0.y,y1) YSTEP(2,cur.B0.z,Cc0.z,y2) YSTEP(3,cur.B0.w,Cc0.w,y3)
    YSTEP(4,cur.B1.x,Cc1.x,y0) YSTEP(5,cur.B1.y,Cc1.y,y1) YSTEP(6,cur.B1.z,Cc1.z,y2) YSTEP(7,cur.B1.w,Cc1.w,y3)
    YSTEP(8,cur.B2.x,Cc2.x,y0) YSTEP(9,cur.B2.y,Cc2.y,y1) YSTEP(10,cur.B2.z,Cc2.z,y2) YSTEP(11,cur.B2.w,Cc2.w,y3)
    YSTEP(12,cur.B3.x,Cc3.x,y0) YSTEP(13,cur.B3.y,Cc3.y,y1) YSTEP(14,cur.B3.z,Cc3.z,y2) YSTEP(15,cur.B3.w,Cc3.w,y3)
    #undef YSTEP
    yb[(size_t)pcur*DIC] = fmaf(cur.uv, Dv, (y0+y1)+(y2+y3));
    cur = nxt; Cc0 = Cn0; Cc1 = Cn1; Cc2 = Cn2; Cc3 = Cn3; pcur = pn;
  }
}

// ---------------- fused tail: combine + out_norm + silu(z) + out_proj + residual
//                  + ln2 + fc1 + gelu + fc2 + residual -> out
// block = (s, pg of 16 px); grid 384. xv tile lives in LDS only.
__global__ __launch_bounds__(256) void k_tail(const float* __restrict__ ys_t,
    const float* __restrict__ z_t, const float* __restrict__ ong, const float* __restrict__ onb,
    const float* __restrict__ Wop, const float* __restrict__ x_cmaj,
    const float* __restrict__ g2, const float* __restrict__ b2n,
    const float* __restrict__ w1, const float* __restrict__ b1,
    const float* __restrict__ w2, const float* __restrict__ b2,
    float* __restrict__ out){
  __shared__ float yt[128*17];    // 2176
  __shared__ float xvt[64*17];    // 1088
  __shared__ float ts[64*17];     // 1088
  int s = blockIdx.x >> 6; int pg = blockIdx.x & 63;
  int tid = threadIdx.x;
  // --- combine + out_norm LN(128) + silu(z) ---
  {
    int wv = __builtin_amdgcn_readfirstlane(tid>>6); int lane = tid&63;
    int d0 = lane, d1 = lane+64;
    for (int i=0;i<4;++i){
      int px = i*4 + wv; int p = pg*16 + px;
      const float* yb = ys_t + ((size_t)(s*4)*L2 + p)*DIC;
      float ya = yb[d0] + yb[(size_t)L2*DIC + d0] + yb[(size_t)2*L2*DIC + d0] + yb[(size_t)3*L2*DIC + d0];
      float yc = yb[d1] + yb[(size_t)L2*DIC + d1] + yb[(size_t)2*L2*DIC + d1] + yb[(size_t)3*L2*DIC + d1];
      float sm = ya+yc, sq = ya*ya+yc*yc;
      for (int m=1;m<64;m<<=1){ sm+=__shfl_xor(sm,m,64); sq+=__shfl_xor(sq,m,64); }
      float mean = sm*(1.f/128.f); float var = sq*(1.f/128.f)-mean*mean;
      float rs = rsqrtf(var + 1e-5f);
      float yn0 = (ya-mean)*rs*ong[d0] + onb[d0];
      float yn1 = (yc-mean)*rs*ong[d1] + onb[d1];
      float zv0 = z_t[((size_t)s*DIC+d0)*L2 + p];
      float zv1 = z_t[((size_t)s*DIC+d1)*L2 + p];
      yt[d0*17 + px] = yn0 * fsilu(zv0);
      yt[d1*17 + px] = yn1 * fsilu(zv1);
    }
  }
  __syncthreads();
  // --- out_proj + residual -> xvt (LDS) ---
  {
    int px = tid & 15; int cgp = tid >> 4;   // per-lane (wave=64: do NOT readfirstlane)
    int c0 = cgp*4;
    float a0=0.f,a1=0.f,a2=0.f,a3=0.f;
    for (int d=0; d<DIC; ++d){
      float yv = yt[d*17 + px];
      a0 = fmaf(Wop[(c0+0)*DIC + d], yv, a0);
      a1 = fmaf(Wop[(c0+1)*DIC + d], yv, a1);
      a2 = fmaf(Wop[(c0+2)*DIC + d], yv, a2);
      a3 = fmaf(Wop[(c0+3)*DIC + d], yv, a3);
    }
    int p = pg*16 + px;
    size_t base = ((size_t)s*CCH + c0)*L2 + p;
    xvt[(c0+0)*17 + px] = x_cmaj[base]      + a0;
    xvt[(c0+1)*17 + px] = x_cmaj[base+L2]   + a1;
    xvt[(c0+2)*17 + px] = x_cmaj[base+2*L2] + a2;
    xvt[(c0+3)*17 + px] = x_cmaj[base+3*L2] + a3;
  }
  __syncthreads();
  // --- ln2 + fc1 + gelu ---
  int px = tid & 15; int cgp = tid >> 4;   // 16 groups of 4
  float sm=0.f, sq=0.f;
  for (int c=0;c<64;++c){ float v = xvt[c*17+px]; sm+=v; sq+=v*v; }
  float mean = sm*(1.f/64.f);
  float rs = rsqrtf(sq*(1.f/64.f) - mean*mean + 1e-5f);
  int o0 = cgp*4;
  float t[4];
  #pragma unroll
  for (int oi=0;oi<4;++oi) t[oi] = b1[o0+oi];
  for (int c=0;c<64;++c){
    float xn = (xvt[c*17+px]-mean)*rs*g2[c] + b2n[c];
    #pragma unroll
    for (int oi=0;oi<4;++oi) t[oi] = fmaf(xn, w1[(o0+oi)*64 + c], t[oi]);
  }
  #pragma unroll
  for (int oi=0;oi<4;++oi) ts[(o0+oi)*17 + px] = fgelu(t[oi]);
  __syncthreads();
  // --- fc2 + residual -> out ---
  int c0 = cgp*4;
  float acc[4];
  #pragma unroll
  for (int ci=0;ci<4;++ci) acc[ci] = xvt[(c0+ci)*17+px] + b2[c0+ci];
  for (int o=0;o<64;++o){
    float tv = ts[o*17+px];
    #pragma unroll
    for (int ci=0;ci<4;++ci) acc[ci] = fmaf(tv, w2[(c0+ci)*64 + o], acc[ci]);
  }
  int p = pg*16 + px;
  #pragma unroll
  for (int ci=0;ci<4;++ci) out[((size_t)s*CCH + c0+ci)*L2 + p] = acc[ci];
}

extern "C" void kernel_launch(void* const* d_in, const int* in_sizes, int n_in,
                              void* d_out, int out_size, void* d_ws, size_t ws_size,
                              hipStream_t stream){
  (void)in_sizes; (void)n_in; (void)out_size; (void)ws_size;
  const float* img      = (const float*)d_in[0];
  const float* dz       = (const float*)d_in[1];
  const float* sg       = (const float*)d_in[2];
  const float* norm_g   = (const float*)d_in[3];
  const float* norm_b   = (const float*)d_in[4];
  const float* gn1_g    = (const float*)d_in[5];
  const float* gn1_b    = (const float*)d_in[6];
  const float* conv1_w  = (const float*)d_in[7];
  const float* conv1_b  = (const float*)d_in[8];
  const float* gn2_g    = (const float*)d_in[9];
  const float* gn2_b    = (const float*)d_in[10];
  const float* conv2_w  = (const float*)d_in[11];
  const float* conv2_b  = (const float*)d_in[12];
  const float* skip_w   = (const float*)d_in[13];
  const float* skip_b   = (const float*)d_in[14];
  const float* ln1_g    = (const float*)d_in[15];
  const float* ln1_b    = (const float*)d_in[16];
  const float* ln2_g    = (const float*)d_in[17];
  const float* ln2_b    = (const float*)d_in[18];
  const float* in_proj_w= (const float*)d_in[19];
  const float* dwconv_w = (const float*)d_in[20];
  const float* dwconv_b = (const float*)d_in[21];
  const float* x_proj_w = (const float*)d_in[22];
  const float* dt_proj_w= (const float*)d_in[23];
  const float* dt_proj_b= (const float*)d_in[24];
  const float* A_logs   = (const float*)d_in[25];
  const float* Ds       = (const float*)d_in[26];
  const float* out_norm_g = (const float*)d_in[27];
  const float* out_norm_b = (const float*)d_in[28];
  const float* out_proj_w = (const float*)d_in[29];
  const float* fc1_w    = (const float*)d_in[30];
  const float* fc1_b    = (const float*)d_in[31];
  const float* fc2_w    = (const float*)d_in[32];
  const float* fc2_b    = (const float*)d_in[33];

  float* ws = (float*)d_ws;
  float* x3c    = ws;                       // 1,179,648
  float* xact1  = x3c    + 1179648;         // 1,253,376 (padded)
  float* h1     = xact1  + 1253376;         // 393,216
  float* xact2  = h1     + 393216;          // 417,792 (padded)
  float* xp     = xact2  + 417792;          // 393,216
  float* x_cmaj = xp     + 393216;          // 393,216
  float* z_t    = x_cmaj + 393216;          // 786,432
  float* xc     = z_t    + 786432;          // 786,432
  float* xconv  = xc     + 786432;          // 786,432
  float* hole   = xconv  + 786432;          // 884,736 (tail of prodA alias)
  float* dtp    = hole   + 884736;          // 3,145,728 (hosts conv1 partials first)
  float* ys_t   = dtp    + 3145728;         // 3,145,728 (hosts conv2 partials first)
  float* statsb = ys_t   + 3145728;         // 960 floats: psum1(96) psq1(96) psum2(384) psq2(384)
  float* psum1  = statsb;
  float* psq1   = statsb + 96;
  float* psum2  = statsb + 192;
  float* psq2   = statsb + 576;
  // aliases into dead regions
  float* part1  = dtp;              // conv1 partials (8 x 393216) — consumed before dtp written
  float* part2  = ys_t;             // conv2 partials (3 x 393216) — consumed before ys_t written
  float* hend   = x3c;              // 1,572,864 (x3c+xact1 dead after conv2_split/conv1)
  float* prodA  = xconv;            // 1,572,864 (xconv dead after xproj_dt; extends into hole)
  float* u_t    = h1;               // 786,432 (h1+xact2 dead after gnact2/conv2_split)
  float* Bp     = xp;               // 393,216 (xp dead after ln1_inproj)
  float* Cp     = xc;               // 393,216 (xc dead after dwconv)

  k_ln2d<<<96, 256, 0, stream>>>(img, dz, sg, norm_g, norm_b, x3c, psum1, psq1);
  k_gnact_pad<<<6*C3, 256, 0, stream>>>(x3c, psum1, psq1, gn1_g, gn1_b, C3, 16,
                                        1.f/(C3*L2), 1e-5f, xact1);
  k_conv1_split<<<1536, 256, 0, stream>>>(xact1, conv1_w, part1);
  k_reduce1<<<384, 256, 0, stream>>>(part1, conv1_b, h1, psum2, psq2);
  k_gnact_pad<<<6*CCH, 256, 0, stream>>>(h1, psum2, psq2, gn2_g, gn2_b, CCH, 64,
                                         1.f/(CCH*L2), 1e-5f, xact2);
  k_conv2_split<<<576, 256, 0, stream>>>(xact2, x3c, conv2_w, skip_w, part2);
  k_reduce2<<<384, 256, 0, stream>>>(part2, conv2_b, skip_b, xp, x_cmaj);
  k_ln1_inproj<<<384, 256, 0, stream>>>(xp, ln1_g, ln1_b, in_proj_w, xc, z_t);
  k_dwconv<<<768, 256, 0, stream>>>(xc, dwconv_w, dwconv_b, xconv);
  k_xproj_dt<<<384, 256, 0, stream>>>(xconv, x_proj_w, dt_proj_w, dt_proj_b, dtp, Bp, Cp, u_t);
  k_scan_part3<<<384, 256, 0, stream>>>(dtp, u_t, Bp, A_logs, hend, prodA);
  k_scan_fix3<<<192, 256, 0, stream>>>(hend, prodA);
  k_scan_y3<<<384, 256, 0, stream>>>(dtp, u_t, Bp, Cp, A_logs, Ds, prodA, ys_t);
  k_tail<<<384, 256, 0, stream>>>(ys_t, z_t, out_norm_g, out_norm_b, out_proj_w, x_cmaj,
                                  ln2_g, ln2_b, fc1_w, fc1_b, fc2_w, fc2_b, (float*)d_out);
}